// Round 1
// baseline (1590.499 us; speedup 1.0000x reference)
//
#include <hip/hip_runtime.h>
#include <hip/hip_bf16.h>
#include <cstdint>
#include <cstddef>

// ---------------------------------------------------------------------------
// LlamaDecoderLayer on MI355X (gfx950).
// All matmuls in f16 MFMA (fp32 accumulate): threshold is bf16-floor (0.1525),
// f16 has more mantissa than bf16 and all activations here are O(1-10).
// GEMM = m97 structure: 128x128 tile, BK=64, 4 waves, global_load_lds(16B).
// ---------------------------------------------------------------------------

typedef _Float16 f16;
typedef __attribute__((ext_vector_type(8))) _Float16 f16x8;
typedef __attribute__((ext_vector_type(4))) float f32x4;

#define HIDDEN   2048
#define NHEADS   16
#define HEAD_DIM 128
#define INTER    8192
#define BATCH    2
#define SEQ      2048
#define NTOK     (BATCH * SEQ)

__device__ __forceinline__ void async16(void* lds, const void* g) {
    __builtin_amdgcn_global_load_lds(
        (const __attribute__((address_space(1))) void*)g,
        (__attribute__((address_space(3))) void*)lds, 16, 0, 0);
}

// ---------------------------------------------------------------------------
// RMSNorm: fp32 [row][2048] -> f16 [row][2048].  One 256-thread block per row.
// ---------------------------------------------------------------------------
__global__ __launch_bounds__(256)
void rmsnorm_f16(const float* __restrict__ x, const float* __restrict__ w,
                 f16* __restrict__ out)
{
    const int row = blockIdx.x;
    const int tid = threadIdx.x;
    const float* xr = x + (size_t)row * HIDDEN;
    float4 a = ((const float4*)xr)[tid * 2];
    float4 b = ((const float4*)xr)[tid * 2 + 1];
    float ss = a.x*a.x + a.y*a.y + a.z*a.z + a.w*a.w
             + b.x*b.x + b.y*b.y + b.z*b.z + b.w*b.w;
    #pragma unroll
    for (int m = 32; m; m >>= 1) ss += __shfl_xor(ss, m, 64);
    __shared__ float red[4];
    if ((tid & 63) == 0) red[tid >> 6] = ss;
    __syncthreads();
    float tot = red[0] + red[1] + red[2] + red[3];
    float rs = rsqrtf(tot * (1.0f / HIDDEN) + 1e-6f);
    float vals[8] = {a.x, a.y, a.z, a.w, b.x, b.y, b.z, b.w};
    const float* wp = w + tid * 8;
    f16x8 o;
    #pragma unroll
    for (int j = 0; j < 8; ++j) o[j] = (f16)(vals[j] * rs * wp[j]);
    *(f16x8*)(out + (size_t)row * HIDDEN + tid * 8) = o;
}

// ---------------------------------------------------------------------------
// Transpose + convert: fp32 W[K][N] -> f16 Wt[N][K].  32x32 tiles via LDS.
// ---------------------------------------------------------------------------
__global__ __launch_bounds__(256)
void transpose_to_f16(const float* __restrict__ W, f16* __restrict__ Wt,
                      int K, int N)
{
    __shared__ float t[32][33];
    const int tx = threadIdx.x, ty = threadIdx.y;
    const int n0 = blockIdx.x * 32, k0 = blockIdx.y * 32;
    #pragma unroll
    for (int i = 0; i < 4; ++i)
        t[ty + i * 8][tx] = W[(size_t)(k0 + ty + i * 8) * N + n0 + tx];
    __syncthreads();
    #pragma unroll
    for (int i = 0; i < 4; ++i)
        Wt[(size_t)(n0 + ty + i * 8) * K + k0 + tx] = (f16)t[tx][ty + i * 8];
}

// ---------------------------------------------------------------------------
// GEMM C[M,N] = A[M,K] @ B[K,N] with Bt[N][K] (N-major) input.
// 128x128 tile, BK=64, 256 threads = 4 waves (2x2 of 64x64), 16x16x32 f16 MFMA.
// EPI: 0 = head-split f16 out (Q/K/V, *scale)
//      1 = fp32 out = resid + acc   (O-proj, down-proj)
//      2 = f16 out = silu(acc)      (gate)
//      3 = f16 out = acc * mulin    (up)
// ---------------------------------------------------------------------------
template<int EPI>
__global__ __launch_bounds__(256)
void gemm_bt(const f16* __restrict__ A, const f16* __restrict__ Bt,
             int M, int N, int K,
             f16* __restrict__ outh, float* __restrict__ outf,
             const float* __restrict__ resid, const f16* __restrict__ mulin,
             float scale)
{
    __shared__ __align__(16) f16 sA[128 * 64];
    __shared__ __align__(16) f16 sB[128 * 64];
    const int tid  = threadIdx.x;
    const int lane = tid & 63;
    const int wave = tid >> 6;
    const int wr = wave >> 1, wc = wave & 1;
    const int tM = blockIdx.y * 128, tN = blockIdx.x * 128;
    const int r16 = lane & 15, kg = lane >> 4;

    f32x4 acc[4][4] = {};

    const int rowA = tM + (tid >> 3);
    const int rowB = tN + (tid >> 3);
    const int cOff = (tid & 7) * 8;
    char* sAb = (char*)sA;
    char* sBb = (char*)sB;

    for (int k0 = 0; k0 < K; k0 += 64) {
        __syncthreads();   // prior tile's reads done
        #pragma unroll
        for (int i = 0; i < 4; ++i) {
            async16(sAb + i * 4096 + tid * 16,
                    A  + (size_t)(rowA + i * 32) * K + k0 + cOff);
            async16(sBb + i * 4096 + tid * 16,
                    Bt + (size_t)(rowB + i * 32) * K + k0 + cOff);
        }
        __syncthreads();   // compiler drains vmcnt before barrier
        #pragma unroll
        for (int kk = 0; kk < 2; ++kk) {
            f16x8 af[4], bf[4];
            #pragma unroll
            for (int m = 0; m < 4; ++m)
                af[m] = *(const f16x8*)(sA + (wr * 64 + m * 16 + r16) * 64 + kk * 32 + kg * 8);
            #pragma unroll
            for (int n = 0; n < 4; ++n)
                bf[n] = *(const f16x8*)(sB + (wc * 64 + n * 16 + r16) * 64 + kk * 32 + kg * 8);
            #pragma unroll
            for (int m = 0; m < 4; ++m)
                #pragma unroll
                for (int n = 0; n < 4; ++n)
                    acc[m][n] = __builtin_amdgcn_mfma_f32_16x16x32_f16(
                        af[m], bf[n], acc[m][n], 0, 0, 0);
        }
    }

    // epilogue: C row = (lane>>4)*4 + reg, col = lane&15  (m89-verified layout)
    #pragma unroll
    for (int m = 0; m < 4; ++m) {
        #pragma unroll
        for (int n = 0; n < 4; ++n) {
            #pragma unroll
            for (int r = 0; r < 4; ++r) {
                const int row = tM + wr * 64 + m * 16 + kg * 4 + r;
                const int col = tN + wc * 64 + n * 16 + r16;
                const float v = acc[m][n][r];
                if (EPI == 0) {
                    const int b = row >> 11, s2 = row & (SEQ - 1);
                    const int h = col >> 7,  d  = col & (HEAD_DIM - 1);
                    outh[(((size_t)(b * NHEADS + h)) * SEQ + s2) * HEAD_DIM + d] =
                        (f16)(v * scale);
                } else if (EPI == 1) {
                    const size_t idx = (size_t)row * N + col;
                    outf[idx] = resid[idx] + v;
                } else if (EPI == 2) {
                    const size_t idx = (size_t)row * N + col;
                    outh[idx] = (f16)(v / (1.0f + __expf(-v)));
                } else {
                    const size_t idx = (size_t)row * N + col;
                    outh[idx] = (f16)(v * (float)mulin[idx]);
                }
            }
        }
    }
}

// ---------------------------------------------------------------------------
// Causal flash attention.  Q,K,V f16 [B*H][S][128] (Q pre-scaled by 1/sqrt(d)).
// Block = 256 thr = 4 waves; each wave owns 16 q-rows; KV tiles of 64.
// Online softmax per q-row; P via per-wave LDS; V transposed in LDS for PV.
// Output: attn[token][hidden] f16.
// ---------------------------------------------------------------------------
__global__ __launch_bounds__(256)
void attn_causal(const f16* __restrict__ Q, const f16* __restrict__ Kp,
                 const f16* __restrict__ V, f16* __restrict__ out)
{
    __shared__ __align__(16) f16 sK [64 * 136];   // [key][d], pad 8 -> 272B rows
    __shared__ __align__(16) f16 sVt[128 * 72];   // [d][key], pad 8 -> 144B rows
    __shared__ __align__(16) f16 sP [4 * 16 * 72];// per-wave [q][key], pad 8

    const int tid  = threadIdx.x;
    const int lane = tid & 63, wave = tid >> 6;
    const int r16 = lane & 15, kg = lane >> 4;
    const int qt = blockIdx.x, bh = blockIdx.y;
    const size_t base = (size_t)bh * SEQ * HEAD_DIM;
    const int q0 = qt * 64 + wave * 16;

    f16x8 qf[4];
    #pragma unroll
    for (int kk = 0; kk < 4; ++kk)
        qf[kk] = *(const f16x8*)(Q + base + (size_t)(q0 + r16) * HEAD_DIM + kk * 32 + kg * 8);

    f32x4 o[8] = {};
    float mr[4] = {-1e30f, -1e30f, -1e30f, -1e30f};
    float lr[4] = {0.f, 0.f, 0.f, 0.f};
    int qrow[4];
    #pragma unroll
    for (int r = 0; r < 4; ++r) qrow[r] = q0 + kg * 4 + r;

    for (int kt = 0; kt <= qt; ++kt) {
        __syncthreads();   // prior tile's PV reads done
        #pragma unroll
        for (int i = 0; i < 4; ++i) {
            const int key = i * 16 + (tid >> 4);
            const int c8  = (tid & 15) * 8;
            *(f16x8*)(sK + key * 136 + c8) =
                *(const f16x8*)(Kp + base + (size_t)(kt * 64 + key) * HEAD_DIM + c8);
            f16x8 v8 = *(const f16x8*)(V + base + (size_t)(kt * 64 + key) * HEAD_DIM + c8);
            #pragma unroll
            for (int j = 0; j < 8; ++j) sVt[(c8 + j) * 72 + key] = v8[j];
        }
        __syncthreads();

        // S = Q @ K^T  (K[key][d] is already "B^T" layout over d)
        f32x4 s[4] = {};
        #pragma unroll
        for (int kk = 0; kk < 4; ++kk)
            #pragma unroll
            for (int n = 0; n < 4; ++n) {
                f16x8 kf = *(const f16x8*)(sK + (n * 16 + r16) * 136 + kk * 32 + kg * 8);
                s[n] = __builtin_amdgcn_mfma_f32_16x16x32_f16(qf[kk], kf, s[n], 0, 0, 0);
            }

        // mask + online softmax (rows live in lanes with same kg; reduce over 16)
        #pragma unroll
        for (int r = 0; r < 4; ++r) {
            float pv[4];
            float rowmax = -1e30f;
            #pragma unroll
            for (int n = 0; n < 4; ++n) {
                const int key = kt * 64 + n * 16 + r16;
                const float v = (key <= qrow[r]) ? s[n][r] : -1e30f;
                pv[n] = v;
                rowmax = fmaxf(rowmax, v);
            }
            #pragma unroll
            for (int msk = 8; msk; msk >>= 1)
                rowmax = fmaxf(rowmax, __shfl_xor(rowmax, msk, 64));
            const float nm = fmaxf(mr[r], rowmax);
            const float sc = __expf(mr[r] - nm);
            mr[r] = nm;
            float rsum = 0.f;
            #pragma unroll
            for (int n = 0; n < 4; ++n) {
                const float p = __expf(pv[n] - nm);   // masked -> exp(-huge) = 0
                rsum += p;
                sP[wave * 1152 + (kg * 4 + r) * 72 + n * 16 + r16] = (f16)p;
            }
            #pragma unroll
            for (int msk = 8; msk; msk >>= 1) rsum += __shfl_xor(rsum, msk, 64);
            lr[r] = lr[r] * sc + rsum;
            #pragma unroll
            for (int d = 0; d < 8; ++d) o[d][r] *= sc;
        }
        __syncthreads();   // P visible before PV reads

        // O += P @ V   (A = P[q][key], B = Vt[d][key])
        #pragma unroll
        for (int kk = 0; kk < 2; ++kk) {
            f16x8 pf = *(const f16x8*)(sP + wave * 1152 + r16 * 72 + kk * 32 + kg * 8);
            #pragma unroll
            for (int d = 0; d < 8; ++d) {
                f16x8 vf = *(const f16x8*)(sVt + (d * 16 + r16) * 72 + kk * 32 + kg * 8);
                o[d] = __builtin_amdgcn_mfma_f32_16x16x32_f16(pf, vf, o[d], 0, 0, 0);
            }
        }
    }

    const int b = bh >> 4, h = bh & 15;
    #pragma unroll
    for (int r = 0; r < 4; ++r) {
        const float inv = 1.0f / lr[r];
        const int q = qt * 64 + wave * 16 + kg * 4 + r;
        const size_t rowb = ((size_t)(b * SEQ + q)) * HIDDEN + h * HEAD_DIM;
        #pragma unroll
        for (int d = 0; d < 8; ++d)
            out[rowb + d * 16 + r16] = (f16)(o[d][r] * inv);
    }
}

// ---------------------------------------------------------------------------
extern "C" void kernel_launch(void* const* d_in, const int* in_sizes, int n_in,
                              void* d_out, int out_size, void* d_ws, size_t ws_size,
                              hipStream_t stream)
{
    const float* hs  = (const float*)d_in[0];
    const float* wq  = (const float*)d_in[1];
    const float* wk  = (const float*)d_in[2];
    const float* wv  = (const float*)d_in[3];
    const float* wo  = (const float*)d_in[4];
    const float* wg  = (const float*)d_in[5];
    const float* wu  = (const float*)d_in[6];
    const float* wd  = (const float*)d_in[7];
    const float* ln1 = (const float*)d_in[8];
    const float* ln2 = (const float*)d_in[9];
    float* out = (float*)d_out;
    char*  ws  = (char*)d_ws;

    // workspace layout (~240 MB, all 256B-aligned); hbuf aliases dead wqT..wgT,
    // sg aliases dead q/k/v/attn.
    f16*   wqT   = (f16*)(ws + 0);
    f16*   wkT   = (f16*)(ws + 8388608);
    f16*   wvT   = (f16*)(ws + 16777216);
    f16*   woT   = (f16*)(ws + 25165824);
    f16*   wgT   = (f16*)(ws + 33554432);
    f16*   wuT   = (f16*)(ws + 67108864);
    f16*   wdT   = (f16*)(ws + 100663296);
    f16*   x1    = (f16*)(ws + 134217728);   // also x2
    f16*   qb    = (f16*)(ws + 150994944);
    f16*   kb    = (f16*)(ws + 167772160);
    f16*   vb    = (f16*)(ws + 184549376);
    f16*   attnb = (f16*)(ws + 201326592);
    f16*   sg    = (f16*)(ws + 150994944);   // alias over qb..attnb (dead then)
    float* hid2  = (float*)(ws + 218103808);
    f16*   hbuf  = (f16*)(ws + 0);           // alias over wqT..wgT (dead then)

    const dim3 tb(32, 8);
    const float qscale = 0.08838834764831845f;  // 1/sqrt(128)

    // x1 = rmsnorm(hs, ln1)
    rmsnorm_f16<<<NTOK, 256, 0, stream>>>(hs, ln1, x1);

    // transpose weights -> f16 [N][K]
    transpose_to_f16<<<dim3(64, 64),  tb, 0, stream>>>(wq, wqT, HIDDEN, HIDDEN);
    transpose_to_f16<<<dim3(64, 64),  tb, 0, stream>>>(wk, wkT, HIDDEN, HIDDEN);
    transpose_to_f16<<<dim3(64, 64),  tb, 0, stream>>>(wv, wvT, HIDDEN, HIDDEN);
    transpose_to_f16<<<dim3(64, 64),  tb, 0, stream>>>(wo, woT, HIDDEN, HIDDEN);
    transpose_to_f16<<<dim3(256, 64), tb, 0, stream>>>(wg, wgT, HIDDEN, INTER);
    transpose_to_f16<<<dim3(256, 64), tb, 0, stream>>>(wu, wuT, HIDDEN, INTER);
    transpose_to_f16<<<dim3(64, 256), tb, 0, stream>>>(wd, wdT, INTER, HIDDEN);

    // QKV projections (head-split, Q pre-scaled)
    const dim3 gP(HIDDEN / 128, NTOK / 128);     // (16, 32)
    gemm_bt<0><<<gP, 256, 0, stream>>>(x1, wqT, NTOK, HIDDEN, HIDDEN,
                                       qb, nullptr, nullptr, nullptr, qscale);
    gemm_bt<0><<<gP, 256, 0, stream>>>(x1, wkT, NTOK, HIDDEN, HIDDEN,
                                       kb, nullptr, nullptr, nullptr, 1.0f);
    gemm_bt<0><<<gP, 256, 0, stream>>>(x1, wvT, NTOK, HIDDEN, HIDDEN,
                                       vb, nullptr, nullptr, nullptr, 1.0f);

    // attention
    attn_causal<<<dim3(SEQ / 64, BATCH * NHEADS), 256, 0, stream>>>(qb, kb, vb, attnb);

    // O-projection + residual -> hid2 (fp32)
    gemm_bt<1><<<gP, 256, 0, stream>>>(attnb, woT, NTOK, HIDDEN, HIDDEN,
                                       nullptr, hid2, hs, nullptr, 0.f);

    // x2 = rmsnorm(hid2, ln2)
    rmsnorm_f16<<<NTOK, 256, 0, stream>>>(hid2, ln2, x1);

    // MLP
    const dim3 gI(INTER / 128, NTOK / 128);      // (64, 32)
    gemm_bt<2><<<gI, 256, 0, stream>>>(x1, wgT, NTOK, INTER, HIDDEN,
                                       sg, nullptr, nullptr, nullptr, 0.f);
    gemm_bt<3><<<gI, 256, 0, stream>>>(x1, wuT, NTOK, INTER, HIDDEN,
                                       hbuf, nullptr, nullptr, sg, 0.f);
    gemm_bt<1><<<gP, 256, 0, stream>>>(hbuf, wdT, NTOK, HIDDEN, INTER,
                                       nullptr, out, hid2, nullptr, 0.f);
}

// Round 2
// 1390.612 us; speedup vs baseline: 1.1437x; 1.1437x over previous
//
#include <hip/hip_runtime.h>
#include <hip/hip_bf16.h>
#include <cstdint>
#include <cstddef>

// ---------------------------------------------------------------------------
// LlamaDecoderLayer on MI355X (gfx950).
// All matmuls in f16 MFMA (fp32 accumulate).
// R2: V projection writes V^T per head; attention stages V^T coalesced
//     (kills the 7.4e7 LDS bank-conflict cycles from the in-kernel scatter
//     transpose), drops the per-wave sP barrier, adds setprio around MFMA.
// ---------------------------------------------------------------------------

typedef _Float16 f16;
typedef __attribute__((ext_vector_type(8))) _Float16 f16x8;
typedef __attribute__((ext_vector_type(4))) float f32x4;

#define HIDDEN   2048
#define NHEADS   16
#define HEAD_DIM 128
#define INTER    8192
#define BATCH    2
#define SEQ      2048
#define NTOK     (BATCH * SEQ)

__device__ __forceinline__ void async16(void* lds, const void* g) {
    __builtin_amdgcn_global_load_lds(
        (const __attribute__((address_space(1))) void*)g,
        (__attribute__((address_space(3))) void*)lds, 16, 0, 0);
}

// ---------------------------------------------------------------------------
// RMSNorm: fp32 [row][2048] -> f16 [row][2048].  One 256-thread block per row.
// ---------------------------------------------------------------------------
__global__ __launch_bounds__(256)
void rmsnorm_f16(const float* __restrict__ x, const float* __restrict__ w,
                 f16* __restrict__ out)
{
    const int row = blockIdx.x;
    const int tid = threadIdx.x;
    const float* xr = x + (size_t)row * HIDDEN;
    float4 a = ((const float4*)xr)[tid * 2];
    float4 b = ((const float4*)xr)[tid * 2 + 1];
    float ss = a.x*a.x + a.y*a.y + a.z*a.z + a.w*a.w
             + b.x*b.x + b.y*b.y + b.z*b.z + b.w*b.w;
    #pragma unroll
    for (int m = 32; m; m >>= 1) ss += __shfl_xor(ss, m, 64);
    __shared__ float red[4];
    if ((tid & 63) == 0) red[tid >> 6] = ss;
    __syncthreads();
    float tot = red[0] + red[1] + red[2] + red[3];
    float rs = rsqrtf(tot * (1.0f / HIDDEN) + 1e-6f);
    float vals[8] = {a.x, a.y, a.z, a.w, b.x, b.y, b.z, b.w};
    const float* wp = w + tid * 8;
    f16x8 o;
    #pragma unroll
    for (int j = 0; j < 8; ++j) o[j] = (f16)(vals[j] * rs * wp[j]);
    *(f16x8*)(out + (size_t)row * HIDDEN + tid * 8) = o;
}

// ---------------------------------------------------------------------------
// Transpose + convert: fp32 W[K][N] -> f16 Wt[N][K].  32x32 tiles via LDS.
// ---------------------------------------------------------------------------
__global__ __launch_bounds__(256)
void transpose_to_f16(const float* __restrict__ W, f16* __restrict__ Wt,
                      int K, int N)
{
    __shared__ float t[32][33];
    const int tx = threadIdx.x, ty = threadIdx.y;
    const int n0 = blockIdx.x * 32, k0 = blockIdx.y * 32;
    #pragma unroll
    for (int i = 0; i < 4; ++i)
        t[ty + i * 8][tx] = W[(size_t)(k0 + ty + i * 8) * N + n0 + tx];
    __syncthreads();
    #pragma unroll
    for (int i = 0; i < 4; ++i)
        Wt[(size_t)(n0 + ty + i * 8) * K + k0 + tx] = (f16)t[tx][ty + i * 8];
}

// ---------------------------------------------------------------------------
// GEMM C[M,N] = A[M,K] @ B[K,N] with Bt[N][K] (N-major) input.
// 128x128 tile, BK=64, 256 threads = 4 waves (2x2 of 64x64), 16x16x32 f16 MFMA.
// EPI: 0 = head-split f16 out [bh][s][d] (Q/K, *scale)
//      1 = fp32 out = resid + acc   (O-proj, down-proj)
//      2 = f16 out = silu(acc)      (gate)
//      3 = f16 out = acc * mulin    (up)
//      4 = head-split TRANSPOSED f16 out [bh][d][s]  (V)
// ---------------------------------------------------------------------------
template<int EPI>
__global__ __launch_bounds__(256)
void gemm_bt(const f16* __restrict__ A, const f16* __restrict__ Bt,
             int M, int N, int K,
             f16* __restrict__ outh, float* __restrict__ outf,
             const float* __restrict__ resid, const f16* __restrict__ mulin,
             float scale)
{
    __shared__ __align__(16) f16 sA[128 * 64];
    __shared__ __align__(16) f16 sB[128 * 64];
    const int tid  = threadIdx.x;
    const int lane = tid & 63;
    const int wave = tid >> 6;
    const int wr = wave >> 1, wc = wave & 1;
    const int tM = blockIdx.y * 128, tN = blockIdx.x * 128;
    const int r16 = lane & 15, kg = lane >> 4;

    f32x4 acc[4][4] = {};

    const int rowA = tM + (tid >> 3);
    const int rowB = tN + (tid >> 3);
    const int cOff = (tid & 7) * 8;
    char* sAb = (char*)sA;
    char* sBb = (char*)sB;

    for (int k0 = 0; k0 < K; k0 += 64) {
        __syncthreads();   // prior tile's reads done
        #pragma unroll
        for (int i = 0; i < 4; ++i) {
            async16(sAb + i * 4096 + tid * 16,
                    A  + (size_t)(rowA + i * 32) * K + k0 + cOff);
            async16(sBb + i * 4096 + tid * 16,
                    Bt + (size_t)(rowB + i * 32) * K + k0 + cOff);
        }
        __syncthreads();   // compiler drains vmcnt before barrier
        #pragma unroll
        for (int kk = 0; kk < 2; ++kk) {
            f16x8 af[4], bf[4];
            #pragma unroll
            for (int m = 0; m < 4; ++m)
                af[m] = *(const f16x8*)(sA + (wr * 64 + m * 16 + r16) * 64 + kk * 32 + kg * 8);
            #pragma unroll
            for (int n = 0; n < 4; ++n)
                bf[n] = *(const f16x8*)(sB + (wc * 64 + n * 16 + r16) * 64 + kk * 32 + kg * 8);
            #pragma unroll
            for (int m = 0; m < 4; ++m)
                #pragma unroll
                for (int n = 0; n < 4; ++n)
                    acc[m][n] = __builtin_amdgcn_mfma_f32_16x16x32_f16(
                        af[m], bf[n], acc[m][n], 0, 0, 0);
        }
    }

    // epilogue: C row = (lane>>4)*4 + reg, col = lane&15  (m89-verified layout)
    #pragma unroll
    for (int m = 0; m < 4; ++m) {
        #pragma unroll
        for (int n = 0; n < 4; ++n) {
            #pragma unroll
            for (int r = 0; r < 4; ++r) {
                const int row = tM + wr * 64 + m * 16 + kg * 4 + r;
                const int col = tN + wc * 64 + n * 16 + r16;
                const float v = acc[m][n][r];
                if (EPI == 0) {
                    const int b = row >> 11, s2 = row & (SEQ - 1);
                    const int h = col >> 7,  d  = col & (HEAD_DIM - 1);
                    outh[(((size_t)(b * NHEADS + h)) * SEQ + s2) * HEAD_DIM + d] =
                        (f16)(v * scale);
                } else if (EPI == 1) {
                    const size_t idx = (size_t)row * N + col;
                    outf[idx] = resid[idx] + v;
                } else if (EPI == 2) {
                    const size_t idx = (size_t)row * N + col;
                    outh[idx] = (f16)(v / (1.0f + __expf(-v)));
                } else if (EPI == 3) {
                    const size_t idx = (size_t)row * N + col;
                    outh[idx] = (f16)(v * (float)mulin[idx]);
                } else {   // EPI == 4: V transposed per head -> [bh][d][s]
                    const int b = row >> 11, s2 = row & (SEQ - 1);
                    const int h = col >> 7,  d  = col & (HEAD_DIM - 1);
                    outh[(((size_t)(b * NHEADS + h)) * HEAD_DIM + d) * SEQ + s2] =
                        (f16)v;
                }
            }
        }
    }
}

// ---------------------------------------------------------------------------
// Causal flash attention.  Q,K f16 [B*H][S][128] (Q pre-scaled by 1/sqrt(d)),
// Vt f16 [B*H][128][S] (pre-transposed by the V-proj epilogue).
// Block = 256 thr = 4 waves; each wave owns 16 q-rows; KV tiles of 64.
// Online softmax per q-row; P via per-wave LDS (no barrier needed for it).
// Output: attn[token][hidden] f16.
// ---------------------------------------------------------------------------
__global__ __launch_bounds__(256)
void attn_causal(const f16* __restrict__ Q, const f16* __restrict__ Kp,
                 const f16* __restrict__ Vt, f16* __restrict__ out)
{
    __shared__ __align__(16) f16 sK [64 * 136];   // [key][d], pad 8
    __shared__ __align__(16) f16 sVt[128 * 72];   // [d][key], pad 8
    __shared__ __align__(16) f16 sP [4 * 16 * 72];// per-wave [q][key], pad 8

    const int tid  = threadIdx.x;
    const int lane = tid & 63, wave = tid >> 6;
    const int r16 = lane & 15, kg = lane >> 4;
    const int qt = gridDim.x - 1 - blockIdx.x;    // heavy tiles dispatch first
    const int bh = blockIdx.y;
    const size_t base  = (size_t)bh * SEQ * HEAD_DIM;
    const size_t baseT = (size_t)bh * HEAD_DIM * SEQ;
    const int q0 = qt * 64 + wave * 16;

    f16x8 qf[4];
    #pragma unroll
    for (int kk = 0; kk < 4; ++kk)
        qf[kk] = *(const f16x8*)(Q + base + (size_t)(q0 + r16) * HEAD_DIM + kk * 32 + kg * 8);

    f32x4 o[8] = {};
    float mr[4] = {-1e30f, -1e30f, -1e30f, -1e30f};
    float lr[4] = {0.f, 0.f, 0.f, 0.f};
    int qrow[4];
    #pragma unroll
    for (int r = 0; r < 4; ++r) qrow[r] = q0 + kg * 4 + r;

    for (int kt = 0; kt <= qt; ++kt) {
        __syncthreads();   // prior tile's PV reads done
        // K tile: [key][d], vectorized, conflict-free
        #pragma unroll
        for (int i = 0; i < 4; ++i) {
            const int key = i * 16 + (tid >> 4);
            const int c8  = (tid & 15) * 8;
            *(f16x8*)(sK + key * 136 + c8) =
                *(const f16x8*)(Kp + base + (size_t)(kt * 64 + key) * HEAD_DIM + c8);
        }
        // V^T tile: [d][key], coalesced rows from pre-transposed global
        #pragma unroll
        for (int it = 0; it < 4; ++it) {
            const int idx = it * 256 + tid;       // 0..1023
            const int d = idx >> 3, key0 = (idx & 7) * 8;
            *(f16x8*)(sVt + d * 72 + key0) =
                *(const f16x8*)(Vt + baseT + (size_t)d * SEQ + kt * 64 + key0);
        }
        __syncthreads();

        // S = Q @ K^T
        f32x4 s[4] = {};
        __builtin_amdgcn_s_setprio(1);
        #pragma unroll
        for (int kk = 0; kk < 4; ++kk)
            #pragma unroll
            for (int n = 0; n < 4; ++n) {
                f16x8 kf = *(const f16x8*)(sK + (n * 16 + r16) * 136 + kk * 32 + kg * 8);
                s[n] = __builtin_amdgcn_mfma_f32_16x16x32_f16(qf[kk], kf, s[n], 0, 0, 0);
            }
        __builtin_amdgcn_s_setprio(0);

        // mask + online softmax (rows live in lanes with same kg; reduce over 16)
        #pragma unroll
        for (int r = 0; r < 4; ++r) {
            float pv[4];
            float rowmax = -1e30f;
            #pragma unroll
            for (int n = 0; n < 4; ++n) {
                const int key = kt * 64 + n * 16 + r16;
                const float v = (key <= qrow[r]) ? s[n][r] : -1e30f;
                pv[n] = v;
                rowmax = fmaxf(rowmax, v);
            }
            #pragma unroll
            for (int msk = 8; msk; msk >>= 1)
                rowmax = fmaxf(rowmax, __shfl_xor(rowmax, msk, 64));
            const float nm = fmaxf(mr[r], rowmax);
            const float sc = __expf(mr[r] - nm);
            mr[r] = nm;
            float rsum = 0.f;
            #pragma unroll
            for (int n = 0; n < 4; ++n) {
                const float p = __expf(pv[n] - nm);   // masked -> exp(-huge) = 0
                rsum += p;
                sP[wave * 1152 + (kg * 4 + r) * 72 + n * 16 + r16] = (f16)p;
            }
            #pragma unroll
            for (int msk = 8; msk; msk >>= 1) rsum += __shfl_xor(rsum, msk, 64);
            lr[r] = lr[r] * sc + rsum;
            #pragma unroll
            for (int d = 0; d < 8; ++d) o[d][r] *= sc;
        }
        // NOTE: no __syncthreads here — sP region is strictly per-wave;
        // in-wave LDS ordering (lgkmcnt) is sufficient.

        // O += P @ V   (A = P[q][key], B = Vt[d][key])
        __builtin_amdgcn_s_setprio(1);
        #pragma unroll
        for (int kk = 0; kk < 2; ++kk) {
            f16x8 pf = *(const f16x8*)(sP + wave * 1152 + r16 * 72 + kk * 32 + kg * 8);
            #pragma unroll
            for (int d = 0; d < 8; ++d) {
                f16x8 vf = *(const f16x8*)(sVt + (d * 16 + r16) * 72 + kk * 32 + kg * 8);
                o[d] = __builtin_amdgcn_mfma_f32_16x16x32_f16(pf, vf, o[d], 0, 0, 0);
            }
        }
        __builtin_amdgcn_s_setprio(0);
    }

    const int b = bh >> 4, h = bh & 15;
    #pragma unroll
    for (int r = 0; r < 4; ++r) {
        const float inv = 1.0f / lr[r];
        const int q = qt * 64 + wave * 16 + kg * 4 + r;
        const size_t rowb = ((size_t)(b * SEQ + q)) * HIDDEN + h * HEAD_DIM;
        #pragma unroll
        for (int d = 0; d < 8; ++d)
            out[rowb + d * 16 + r16] = (f16)(o[d][r] * inv);
    }
}

// ---------------------------------------------------------------------------
extern "C" void kernel_launch(void* const* d_in, const int* in_sizes, int n_in,
                              void* d_out, int out_size, void* d_ws, size_t ws_size,
                              hipStream_t stream)
{
    const float* hs  = (const float*)d_in[0];
    const float* wq  = (const float*)d_in[1];
    const float* wk  = (const float*)d_in[2];
    const float* wv  = (const float*)d_in[3];
    const float* wo  = (const float*)d_in[4];
    const float* wg  = (const float*)d_in[5];
    const float* wu  = (const float*)d_in[6];
    const float* wd  = (const float*)d_in[7];
    const float* ln1 = (const float*)d_in[8];
    const float* ln2 = (const float*)d_in[9];
    float* out = (float*)d_out;
    char*  ws  = (char*)d_ws;

    // workspace layout (~240 MB, all 256B-aligned); hbuf aliases dead wqT..wgT,
    // sg aliases dead q/k/v/attn.
    f16*   wqT   = (f16*)(ws + 0);
    f16*   wkT   = (f16*)(ws + 8388608);
    f16*   wvT   = (f16*)(ws + 16777216);
    f16*   woT   = (f16*)(ws + 25165824);
    f16*   wgT   = (f16*)(ws + 33554432);
    f16*   wuT   = (f16*)(ws + 67108864);
    f16*   wdT   = (f16*)(ws + 100663296);
    f16*   x1    = (f16*)(ws + 134217728);   // also x2
    f16*   qb    = (f16*)(ws + 150994944);
    f16*   kb    = (f16*)(ws + 167772160);
    f16*   vtb   = (f16*)(ws + 184549376);   // V transposed per head
    f16*   attnb = (f16*)(ws + 201326592);
    f16*   sg    = (f16*)(ws + 150994944);   // alias over qb..attnb (dead then)
    float* hid2  = (float*)(ws + 218103808);
    f16*   hbuf  = (f16*)(ws + 0);           // alias over wqT..wgT (dead then)

    const dim3 tb(32, 8);
    const float qscale = 0.08838834764831845f;  // 1/sqrt(128)

    // x1 = rmsnorm(hs, ln1)
    rmsnorm_f16<<<NTOK, 256, 0, stream>>>(hs, ln1, x1);

    // transpose weights -> f16 [N][K]
    transpose_to_f16<<<dim3(64, 64),  tb, 0, stream>>>(wq, wqT, HIDDEN, HIDDEN);
    transpose_to_f16<<<dim3(64, 64),  tb, 0, stream>>>(wk, wkT, HIDDEN, HIDDEN);
    transpose_to_f16<<<dim3(64, 64),  tb, 0, stream>>>(wv, wvT, HIDDEN, HIDDEN);
    transpose_to_f16<<<dim3(64, 64),  tb, 0, stream>>>(wo, woT, HIDDEN, HIDDEN);
    transpose_to_f16<<<dim3(256, 64), tb, 0, stream>>>(wg, wgT, HIDDEN, INTER);
    transpose_to_f16<<<dim3(256, 64), tb, 0, stream>>>(wu, wuT, HIDDEN, INTER);
    transpose_to_f16<<<dim3(64, 256), tb, 0, stream>>>(wd, wdT, INTER, HIDDEN);

    // QKV projections (head-split, Q pre-scaled, V transposed)
    const dim3 gP(HIDDEN / 128, NTOK / 128);     // (16, 32)
    gemm_bt<0><<<gP, 256, 0, stream>>>(x1, wqT, NTOK, HIDDEN, HIDDEN,
                                       qb, nullptr, nullptr, nullptr, qscale);
    gemm_bt<0><<<gP, 256, 0, stream>>>(x1, wkT, NTOK, HIDDEN, HIDDEN,
                                       kb, nullptr, nullptr, nullptr, 1.0f);
    gemm_bt<4><<<gP, 256, 0, stream>>>(x1, wvT, NTOK, HIDDEN, HIDDEN,
                                       vtb, nullptr, nullptr, nullptr, 1.0f);

    // attention
    attn_causal<<<dim3(SEQ / 64, BATCH * NHEADS), 256, 0, stream>>>(qb, kb, vtb, attnb);

    // O-projection + residual -> hid2 (fp32)
    gemm_bt<1><<<gP, 256, 0, stream>>>(attnb, woT, NTOK, HIDDEN, HIDDEN,
                                       nullptr, hid2, hs, nullptr, 0.f);

    // x2 = rmsnorm(hid2, ln2)
    rmsnorm_f16<<<NTOK, 256, 0, stream>>>(hid2, ln2, x1);

    // MLP
    const dim3 gI(INTER / 128, NTOK / 128);      // (64, 32)
    gemm_bt<2><<<gI, 256, 0, stream>>>(x1, wgT, NTOK, INTER, HIDDEN,
                                       sg, nullptr, nullptr, nullptr, 0.f);
    gemm_bt<3><<<gI, 256, 0, stream>>>(x1, wuT, NTOK, INTER, HIDDEN,
                                       hbuf, nullptr, nullptr, sg, 0.f);
    gemm_bt<1><<<gP, 256, 0, stream>>>(hbuf, wdT, NTOK, HIDDEN, INTER,
                                       nullptr, out, hid2, nullptr, 0.f);
}